// Round 2
// baseline (5517.292 us; speedup 1.0000x reference)
//
#include <hip/hip_runtime.h>
#include <hip/hip_bf16.h>

#define T_STEPS 256
#define BATCH   64
#define DIM_I   256
#define DIM_H   256
#define NBR     8
#define K_DIM   512
#define F_DIM   1024

typedef __attribute__((ext_vector_type(8))) short short8;
typedef __attribute__((ext_vector_type(4))) float floatx4;

__device__ __forceinline__ float sigmoid_fast(float x) {
    return 1.0f / (1.0f + __expf(-x));
}
__device__ __forceinline__ float tanh_fast(float x) {
    return 1.0f - 2.0f / (__expf(2.0f * x) + 1.0f);
}
// fp32 -> bf16 bits, round-to-nearest-even (finite inputs only)
__device__ __forceinline__ short f2bf(float f) {
    unsigned u = __float_as_uint(f);
    u += 0x7FFFu + ((u >> 16) & 1u);
    return (short)(u >> 16);
}

// Grid: 256 blocks x 128 threads (2 waves).
// blockIdx: n = bid & 7 (branch, XCD-swizzled), p = (bid>>3)&1 (batch half),
//           chunk = bid>>4 (16-column H-chunk).
// Per step, block computes z[rows p*32..p*32+31][4 gates x 16 cols] via bf16
// MFMA (fp32 accum); W slice pinned in LDS in exact B-fragment order.
__global__ void __launch_bounds__(128)
durlm_kernel(const float* __restrict__ x,       // [T,B,I] fp32
             const int* __restrict__ dur,       // [T,B]
             const float* __restrict__ weight,  // [N,K,4H] fp32
             const float* __restrict__ bias_i,  // [N,4H] fp32
             const float* __restrict__ bias_h,  // [N,4H] fp32
             float* __restrict__ out,           // [T,N,B,H] fp32
             short* __restrict__ hbuf,          // [2,N,B,H] bf16 bits ping-pong
             unsigned int* __restrict__ counters) // [16] barrier counters
{
    // B-fragment-order W: Wlds[ks][nt][lane][j], 16*4*64*8 bf16 = 64 KB
    __shared__ short Wlds[16 * 4 * 64 * 8];

    const int tid   = threadIdx.x;
    const int lane  = tid & 63;
    const int w     = tid >> 6;          // wave 0..1 -> M-tile
    const int bid   = blockIdx.x;
    const int n     = bid & 7;           // branch
    const int p     = (bid >> 3) & 1;    // batch half
    const int chunk = bid >> 4;          // 0..15
    const int j0    = chunk * 16;
    const int grp   = n * 2 + p;         // barrier group (16 blocks each)

    const int l15  = lane & 15;
    const int quad = lane >> 4;

    // ---- stage W slice into LDS (fp32 -> bf16, B-fragment order), once ----
    {
        const float* Wn = weight + (size_t)n * K_DIM * F_DIM;
        const int fl4 = (tid & 15) * 4;            // f_local base (0..60)
        const int nt  = fl4 >> 4;                  // gate index of this group of 4
        const int c0  = fl4 & 15;                  // column-within-16
        const int fg  = nt * 256 + j0 + c0;        // global f base (16B aligned)
        for (int kk = tid >> 4; kk < K_DIM; kk += 8) {
            float4 wv = *reinterpret_cast<const float4*>(Wn + (size_t)kk * F_DIM + fg);
            int ks = kk >> 5;
            int qr = (kk >> 3) & 3;                // B-fragment quad (from k)
            int j  = kk & 7;                       // register element (from k)
            int base = ((ks * 4 + nt) * 64 + qr * 16 + c0) * 8 + j;
            Wlds[base + 0 * 8] = f2bf(wv.x);
            Wlds[base + 1 * 8] = f2bf(wv.y);
            Wlds[base + 2 * 8] = f2bf(wv.z);
            Wlds[base + 3 * 8] = f2bf(wv.w);
        }
    }

    // ---- per-lane gate biases (fp32) ----
    float bias[4];
#pragma unroll
    for (int nt = 0; nt < 4; ++nt) {
        int f = nt * 256 + j0 + l15;
        bias[nt] = bias_i[n * F_DIM + f] + bias_h[n * F_DIM + f];
    }

    const int rA    = p * 32 + w * 16 + l15;       // A-fragment row (batch idx)
    const int rowD0 = p * 32 + w * 16 + quad * 4;  // D rows rowD0..rowD0+3

    float c_state[4] = {0.f, 0.f, 0.f, 0.f};

    __syncthreads();  // Wlds ready

    for (int t = 0; t < T_STEPS; ++t) {
        const short* hc  = hbuf + ((size_t)(t & 1) * NBR + n) * BATCH * DIM_H;
        short*       hnx = hbuf + ((size_t)((t + 1) & 1) * NBR + n) * BATCH * DIM_H;

        floatx4 acc[4];
#pragma unroll
        for (int nt = 0; nt < 4; ++nt) acc[nt] = (floatx4){0.f, 0.f, 0.f, 0.f};

        const float* xrow = x + ((size_t)t * BATCH + rA) * DIM_I + quad * 8;
        const short* hrow = hc + (size_t)rA * DIM_H + quad * 8;

#pragma unroll
        for (int ks = 0; ks < 16; ++ks) {
            short8 afrag;
            if (ks < 8) {
                const float4* px = reinterpret_cast<const float4*>(xrow + ks * 32);
                float4 a0 = px[0];
                float4 a1 = px[1];
                afrag[0] = f2bf(a0.x); afrag[1] = f2bf(a0.y);
                afrag[2] = f2bf(a0.z); afrag[3] = f2bf(a0.w);
                afrag[4] = f2bf(a1.x); afrag[5] = f2bf(a1.y);
                afrag[6] = f2bf(a1.z); afrag[7] = f2bf(a1.w);
            } else {
                afrag = *reinterpret_cast<const short8*>(hrow + (ks - 8) * 32);
            }
#pragma unroll
            for (int nt = 0; nt < 4; ++nt) {
                short8 bfrag = *reinterpret_cast<const short8*>(
                    &Wlds[((ks * 4 + nt) * 64 + lane) * 8]);
                acc[nt] = __builtin_amdgcn_mfma_f32_16x16x32_bf16(
                    afrag, bfrag, acc[nt], 0, 0, 0);
            }
        }

        // ---- pointwise LSTM epilogue: lane-local (gate g in acc[g][r]) ----
#pragma unroll
        for (int r = 0; r < 4; ++r) {
            int row = rowD0 + r;
            int d   = dur[t * BATCH + row];
            bool freeze = n > (d >> 3);
            float zi = acc[0][r] + bias[0];
            float zf = acc[1][r] + bias[1];
            float zo = acc[2][r] + bias[2];
            float zg = acc[3][r] + bias[3];
            float ig = sigmoid_fast(zi);
            float fg = sigmoid_fast(zf);
            float og = sigmoid_fast(zo);
            float gg = tanh_fast(zg);
            float cn = freeze ? c_state[r] : fg * c_state[r] + ig * gg;
            c_state[r] = cn;
            float hv = og * tanh_fast(cn);
            hnx[(size_t)row * DIM_H + j0 + l15] = f2bf(hv);
            out[(((size_t)t * NBR + n) * BATCH + row) * DIM_H + j0 + l15] = hv;
        }

        // ---- inter-block barrier over the 16 blocks of this (n,p) group ----
        if (t != T_STEPS - 1) {
            __threadfence();   // flush h writes to device scope (cross-XCD)
            __syncthreads();   // all threads of block have written+fenced
            if (tid == 0) {
                __hip_atomic_fetch_add(&counters[grp], 1u, __ATOMIC_RELEASE,
                                       __HIP_MEMORY_SCOPE_AGENT);
                unsigned target = (unsigned)(t + 1) * 16u;
                while (__hip_atomic_load(&counters[grp], __ATOMIC_ACQUIRE,
                                         __HIP_MEMORY_SCOPE_AGENT) < target) {
                    __builtin_amdgcn_s_sleep(1);
                }
            }
            __syncthreads();
        }
    }
}

extern "C" void kernel_launch(void* const* d_in, const int* in_sizes, int n_in,
                              void* d_out, int out_size, void* d_ws, size_t ws_size,
                              hipStream_t stream) {
    const float* x      = (const float*)d_in[0];
    const int*   durp   = (const int*)d_in[1];
    const float* weight = (const float*)d_in[2];
    const float* bias_i = (const float*)d_in[3];
    const float* bias_h = (const float*)d_in[4];
    float* out = (float*)d_out;

    unsigned int* counters = (unsigned int*)d_ws;                 // 1 KB reserved
    short*        hbuf     = (short*)((char*)d_ws + 1024);        // 512 KB bf16 bits

    size_t clear_bytes = 1024 + (size_t)2 * NBR * BATCH * DIM_H * sizeof(short);
    hipMemsetAsync(d_ws, 0, clear_bytes, stream);

    durlm_kernel<<<256, 128, 0, stream>>>(x, durp, weight, bias_i, bias_h,
                                          out, hbuf, counters);
}